// Round 4
// baseline (1045.128 us; speedup 1.0000x reference)
//
#include <hip/hip_runtime.h>

// TextGraph: embed -> 5xMLP(bf16 MFMA) -> he=log(exp(x)) -> per-batch adj-aggregate (moved
// before the GCN GEMM via linearity) -> GEMM+bias -> fused hyperbolic tail (layers 0-2 of
// the reference GCN are dead code: h is rebuilt from graph_node each iteration).
//
// R3 fix: GEMM 5 now writes bf16 (Cb=bufB). The previous fp32 Cf write spanned all of
// d_out and clobbered wT04 (weight 4) WHILE GEMM 5 was reading it -> inf/NaN.

typedef __attribute__((ext_vector_type(8))) short short8;
typedef __attribute__((ext_vector_type(4))) float f32x4;

#define MAXN 0.99999f   // 1 - 1e-5
#define EPSF 1e-15f

#define GLOAD_LDS16(SRC, DST) \
  __builtin_amdgcn_global_load_lds((const __attribute__((address_space(1))) void*)(SRC), \
                                   (__attribute__((address_space(3))) void*)(DST), 16, 0, 0)

__device__ __forceinline__ unsigned short f2bf(float f) {
  unsigned u = __float_as_uint(f);
  u += 0x7FFFu + ((u >> 16) & 1u);
  return (unsigned short)(u >> 16);
}
__device__ __forceinline__ float bf2f(unsigned short h) {
  return __uint_as_float(((unsigned)h) << 16);
}

// ---------------- weight convert + transpose: W[k][n] f32 -> Wt[n][k] bf16 ----------------
__global__ void __launch_bounds__(256) wt_kernel(const float* __restrict__ mlp_w,
                                                 const float* __restrict__ gcn_w,
                                                 unsigned short* __restrict__ wT04,
                                                 unsigned short* __restrict__ wT5) {
  __shared__ float s[32][33];
  const int m = blockIdx.z;
  const float* src = (m < 5) ? (mlp_w + (size_t)m * 1048576) : (gcn_w + (size_t)3 * 1048576);
  unsigned short* dst = (m < 5) ? (wT04 + (size_t)m * 1048576) : wT5;
  const int k0 = blockIdx.x * 32, n0 = blockIdx.y * 32;
  const int tx = threadIdx.x, ty = threadIdx.y;
#pragma unroll
  for (int i = 0; i < 4; i++) s[ty + 8 * i][tx] = src[(size_t)(k0 + ty + 8 * i) * 1024 + n0 + tx];
  __syncthreads();
#pragma unroll
  for (int i = 0; i < 4; i++)
    dst[(size_t)(n0 + ty + 8 * i) * 1024 + k0 + tx] = f2bf(s[tx][ty + 8 * i]);
}

// ---------------- embedding: x0 = tok_w[tok] + pos_w[s] -> bf16 ----------------
__global__ void __launch_bounds__(256) embed_kernel(const int* __restrict__ tokens,
                                                    const float* __restrict__ tok_w,
                                                    const float* __restrict__ pos_w,
                                                    unsigned short* __restrict__ x0) {
  const int row = blockIdx.x, t = threadIdx.x;
  const int s = row % 77;
  const int tok = tokens[row];
  const float4 a = *(const float4*)(tok_w + (size_t)tok * 1024 + t * 4);
  const float4 p = *(const float4*)(pos_w + (size_t)s * 1024 + t * 4);
  ushort4 o;
  o.x = f2bf(a.x + p.x); o.y = f2bf(a.y + p.y); o.z = f2bf(a.z + p.z); o.w = f2bf(a.w + p.w);
  *(ushort4*)(x0 + (size_t)row * 1024 + t * 4) = o;
}

// ---------------- GEMM: C[M,N] = A[M,K](bf16) @ Wt[N,K](bf16)^T, fp32 acc ----------------
// 128x128 tile, BK=64, 4 waves (2x2), 16x16x32 MFMA, global_load_lds staging with
// XOR-swizzled global source (chunk ^= row&7) so ds_read_b128 fragment reads are 2-way max.
__global__ void __launch_bounds__(256) gemm_bf16(const unsigned short* __restrict__ A,
                                                 const unsigned short* __restrict__ Bt,
                                                 const float* __restrict__ bias,
                                                 unsigned short* __restrict__ Cb,
                                                 float* __restrict__ Cf,
                                                 int M, int N, int K, int act) {
  __shared__ __align__(16) unsigned short lds[16384];  // lA [128][64] + lB [128][64] (32KB)
  unsigned short* lA = lds;
  unsigned short* lB = lds + 8192;
  const int t = threadIdx.x;
  const int w = t >> 6, l = t & 63;
  const int wm = w >> 1, wn = w & 1;
  const int lr = l & 15, lk = l >> 4;
  const int row0 = blockIdx.x * 128;
  const int col0 = blockIdx.y * 128;

  f32x4 zero = {0.f, 0.f, 0.f, 0.f};
  f32x4 acc[4][4];
#pragma unroll
  for (int i = 0; i < 4; i++)
#pragma unroll
    for (int j = 0; j < 4; j++) acc[i][j] = zero;

  const int sr = t >> 3;  // staging row within 32-row group
  const int pc = t & 7;   // physical 16B chunk
  const int nk = K >> 6;
  for (int kt = 0; kt < nk; ++kt) {
    const int k0 = kt << 6;
#pragma unroll
    for (int i = 0; i < 4; ++i) {
      const int r = i * 32 + sr;
      const int lc = pc ^ (r & 7);
      GLOAD_LDS16(A + (size_t)(row0 + r) * K + k0 + lc * 8, lA + (i * 256 + t) * 8);
    }
#pragma unroll
    for (int i = 0; i < 4; ++i) {
      const int r = i * 32 + sr;
      const int lc = pc ^ (r & 7);
      GLOAD_LDS16(Bt + (size_t)(col0 + r) * K + k0 + lc * 8, lB + (i * 256 + t) * 8);
    }
    __syncthreads();
#pragma unroll
    for (int kk = 0; kk < 2; ++kk) {
      short8 af[4], bfr[4];
#pragma unroll
      for (int f = 0; f < 4; ++f) {
        const int ra = wm * 64 + f * 16 + lr;
        const int ca = (kk * 4 + lk) ^ (ra & 7);
        af[f] = *(const short8*)(lA + ra * 64 + ca * 8);
        const int rb = wn * 64 + f * 16 + lr;
        const int cb = (kk * 4 + lk) ^ (rb & 7);
        bfr[f] = *(const short8*)(lB + rb * 64 + cb * 8);
      }
#pragma unroll
      for (int i = 0; i < 4; ++i)
#pragma unroll
        for (int j = 0; j < 4; ++j)
          acc[i][j] = __builtin_amdgcn_mfma_f32_16x16x32_bf16(af[i], bfr[j], acc[i][j], 0, 0, 0);
    }
    __syncthreads();
  }

  if (Cb) {
    // bf16 out: repack through LDS for coalesced 16B stores
    unsigned short* lC = lds;  // [128][128] bf16 = 32KB
#pragma unroll
    for (int i = 0; i < 4; ++i)
#pragma unroll
      for (int j = 0; j < 4; ++j)
#pragma unroll
        for (int r = 0; r < 4; ++r) {
          const int row = wm * 64 + i * 16 + lk * 4 + r;
          const int col = wn * 64 + j * 16 + lr;
          float v = acc[i][j][r];
          if (bias) v += bias[col0 + col];
          if (act) v = v / (1.f + __expf(-v));
          lC[row * 128 + col] = f2bf(v);
        }
    __syncthreads();
#pragma unroll
    for (int it = 0; it < 8; ++it) {
      const int idx = it * 256 + t;
      const int row = idx >> 4, cc = idx & 15;
      *(uint4*)(Cb + (size_t)(row0 + row) * N + col0 + cc * 8) =
          *(const uint4*)(lC + row * 128 + cc * 8);
    }
  } else {
#pragma unroll
    for (int i = 0; i < 4; ++i)
#pragma unroll
      for (int j = 0; j < 4; ++j)
#pragma unroll
        for (int r = 0; r < 4; ++r) {
          const int row = wm * 64 + i * 16 + lk * 4 + r;
          const int col = wn * 64 + j * 16 + lr;
          float v = acc[i][j][r];
          if (bias) v += bias[col0 + col];
          if (act) v = v / (1.f + __expf(-v));
          Cf[(size_t)(row0 + row) * N + col0 + col] = v;
        }
  }
}

// ---------------- he = logmap0(expmap0(x)) row-wise, bf16 -> bf16 ----------------
// |expmap0(x)| = tanh(|x|) analytically, so the pair collapses to one scale per row.
__global__ void __launch_bounds__(256) he_kernel(const unsigned short* __restrict__ x,
                                                 unsigned short* __restrict__ he) {
  __shared__ float red[4];
  const int row = blockIdx.x, t = threadIdx.x;
  const ushort4 v = *(const ushort4*)(x + (size_t)row * 1024 + t * 4);
  const float v0 = bf2f(v.x), v1 = bf2f(v.y), v2 = bf2f(v.z), v3 = bf2f(v.w);
  float ss = v0 * v0 + v1 * v1 + v2 * v2 + v3 * v3;
#pragma unroll
  for (int o = 32; o; o >>= 1) ss += __shfl_xor(ss, o, 64);
  if ((t & 63) == 0) red[t >> 6] = ss;
  __syncthreads();
  ss = red[0] + red[1] + red[2] + red[3];
  const float n = fmaxf(sqrtf(ss), EPSF);
  const float s = atanhf(fminf(tanhf(n), MAXN)) / n;
  ushort4 o;
  o.x = f2bf(v0 * s); o.y = f2bf(v1 * s); o.z = f2bf(v2 * s); o.w = f2bf(v3 * s);
  *(ushort4*)(he + (size_t)row * 1024 + t * 4) = o;
}

// ---------------- per-batch aggregate, IN PLACE on he ----------------
// agg_he[b,c,:] = sum_r (edge[b,r,c]!=0) * he[b,r,:]   (linearity: aggregate before GEMM)
// Block (q, b) owns batch b, dim slice [q*256, q*256+256): reads/writes only its own slice.
__global__ void __launch_bounds__(256) agg_kernel(unsigned short* __restrict__ he,
                                                  const int* __restrict__ edge) {
  __shared__ __align__(16) unsigned short ml[77 * 256];  // 39,424 B
  __shared__ unsigned long long bits[77][2];
  const int q = blockIdx.x, b = blockIdx.y, t = threadIdx.x;
  unsigned short* base = he + (size_t)b * 77 * 1024 + q * 256;

  for (int i = t; i < 77 * 32; i += 256) {  // 16B chunks: 32 per row
    const int r = i >> 5, o = (i & 31) * 8;
    *(uint4*)(ml + r * 256 + o) = *(const uint4*)(base + (size_t)r * 1024 + o);
  }
  if (t < 77) {  // adjacency column bitmask: bit r of column t
    unsigned long long b0 = 0, b1 = 0;
    const int* ec = edge + (size_t)b * 77 * 77 + t;
    for (int r = 0; r < 77; r++) {
      if (ec[r * 77] != 0) {
        if (r < 64) b0 |= (1ull << r); else b1 |= (1ull << (r - 64));
      }
    }
    bits[t][0] = b0; bits[t][1] = b1;
  }
  __syncthreads();

  const int w = t >> 6, l = t & 63;
  const int da = 2 * l, db = 128 + 2 * l;  // two ushort2 lanes: 2-way-free LDS access
  for (int c = w; c < 77; c += 4) {
    unsigned long long w0 = bits[c][0], w1 = bits[c][1];
    float a0 = 0.f, a1 = 0.f, c0 = 0.f, c1 = 0.f;
    while (w0) {
      const int r = __builtin_ctzll(w0); w0 &= w0 - 1;
      const ushort2 va = *(const ushort2*)(ml + r * 256 + da);
      const ushort2 vb = *(const ushort2*)(ml + r * 256 + db);
      a0 += bf2f(va.x); a1 += bf2f(va.y); c0 += bf2f(vb.x); c1 += bf2f(vb.y);
    }
    while (w1) {
      const int r = 64 + __builtin_ctzll(w1); w1 &= w1 - 1;
      const ushort2 va = *(const ushort2*)(ml + r * 256 + da);
      const ushort2 vb = *(const ushort2*)(ml + r * 256 + db);
      a0 += bf2f(va.x); a1 += bf2f(va.y); c0 += bf2f(vb.x); c1 += bf2f(vb.y);
    }
    ushort2 oa, ob;
    oa.x = f2bf(a0); oa.y = f2bf(a1); ob.x = f2bf(c0); ob.y = f2bf(c1);
    *(ushort2*)(base + (size_t)c * 1024 + da) = oa;
    *(ushort2*)(base + (size_t)c * 1024 + db) = ob;
  }
}

// ---------------- final tail, IN PLACE on fp32 agg (d_out) ----------------
// out = logmap0(expmap0(leaky(logmap0(expmap0(agg))))) collapses to two row-norm scales.
__global__ void __launch_bounds__(256) tailrow_kernel(float* __restrict__ y) {
  __shared__ float r1[4], r2[4];
  const int row = blockIdx.x, t = threadIdx.x;
  const float4 g = *(const float4*)(y + (size_t)row * 1024 + t * 4);
  float ss = g.x * g.x + g.y * g.y + g.z * g.z + g.w * g.w;
#pragma unroll
  for (int o = 32; o; o >>= 1) ss += __shfl_xor(ss, o, 64);
  if ((t & 63) == 0) r1[t >> 6] = ss;
  __syncthreads();
  ss = r1[0] + r1[1] + r1[2] + r1[3];
  const float n1 = fmaxf(sqrtf(ss), EPSF);
  const float s1 = atanhf(fminf(tanhf(n1), MAXN)) / n1;
  float l0 = g.x * s1, l1 = g.y * s1, l2 = g.z * s1, l3 = g.w * s1;
  l0 = l0 >= 0.f ? l0 : 0.01f * l0;
  l1 = l1 >= 0.f ? l1 : 0.01f * l1;
  l2 = l2 >= 0.f ? l2 : 0.01f * l2;
  l3 = l3 >= 0.f ? l3 : 0.01f * l3;
  float ss2 = l0 * l0 + l1 * l1 + l2 * l2 + l3 * l3;
#pragma unroll
  for (int o = 32; o; o >>= 1) ss2 += __shfl_xor(ss2, o, 64);
  if ((t & 63) == 0) r2[t >> 6] = ss2;
  __syncthreads();
  ss2 = r2[0] + r2[1] + r2[2] + r2[3];
  const float n2 = fmaxf(sqrtf(ss2), EPSF);
  const float s2 = atanhf(fminf(tanhf(n2), MAXN)) / n2;
  float4 o;
  o.x = l0 * s2; o.y = l1 * s2; o.z = l2 * s2; o.w = l3 * s2;
  *(float4*)(y + (size_t)row * 1024 + t * 4) = o;
}

extern "C" void kernel_launch(void* const* d_in, const int* in_sizes, int n_in,
                              void* d_out, int out_size, void* d_ws, size_t ws_size,
                              hipStream_t stream) {
  const int* tokens = (const int*)d_in[0];
  const int* edge = (const int*)d_in[1];
  const float* tok_w = (const float*)d_in[2];
  const float* pos_w = (const float*)d_in[3];
  const float* mlp_w = (const float*)d_in[4];
  const float* mlp_b = (const float*)d_in[5];
  const float* gcn_w = (const float*)d_in[6];
  const float* gcn_b = (const float*)d_in[7];

  const int Mrows = 256 * 77;  // 19712 = 154 * 128
  const int D = 1024;
  const size_t ROWSZ = (size_t)Mrows * D;  // 20,185,088 elements

  // d_ws layout (42.5 MB): bufA (bf16 activations) + wT5 (gcn_w[3]^T bf16)
  unsigned short* bufA = (unsigned short*)d_ws;
  unsigned short* wT5 = bufA + ROWSZ;
  // d_out upper region (dead by the time the final GEMM overwrites d_out with fp32):
  //   bufB (bf16, bytes [0, 40.4M)) + wT04 (5 transposed MLP weights, bytes [40.4M, 50.9M))
  unsigned short* bufB = (unsigned short*)d_out;
  unsigned short* wT04 = bufB + ROWSZ;
  float* aggf = (float*)d_out;

  wt_kernel<<<dim3(32, 32, 6), dim3(32, 8), 0, stream>>>(mlp_w, gcn_w, wT04, wT5);
  embed_kernel<<<Mrows, 256, 0, stream>>>(tokens, tok_w, pos_w, bufA);

  dim3 gg(Mrows / 128, D / 128);
  gemm_bf16<<<gg, 256, 0, stream>>>(bufA, wT04 + 0ull * 1048576, mlp_b + 0,    bufB, nullptr, Mrows, D, D, 1);
  gemm_bf16<<<gg, 256, 0, stream>>>(bufB, wT04 + 1ull * 1048576, mlp_b + 1024, bufA, nullptr, Mrows, D, D, 1);
  gemm_bf16<<<gg, 256, 0, stream>>>(bufA, wT04 + 2ull * 1048576, mlp_b + 2048, bufB, nullptr, Mrows, D, D, 1);
  gemm_bf16<<<gg, 256, 0, stream>>>(bufB, wT04 + 3ull * 1048576, mlp_b + 3072, bufA, nullptr, Mrows, D, D, 1);
  gemm_bf16<<<gg, 256, 0, stream>>>(bufA, wT04 + 4ull * 1048576, mlp_b + 4096, bufB, nullptr, Mrows, D, D, 0);
  he_kernel<<<Mrows, 256, 0, stream>>>(bufB, bufA);
  agg_kernel<<<dim3(4, 256), 256, 0, stream>>>(bufA, edge);
  gemm_bf16<<<gg, 256, 0, stream>>>(bufA, wT5, gcn_b + 3072, nullptr, aggf, Mrows, D, D, 0);
  tailrow_kernel<<<Mrows, 256, 0, stream>>>(aggf);
}